// Round 1
// baseline (479.713 us; speedup 1.0000x reference)
//
#include <hip/hip_runtime.h>
#include <math.h>

// Problem constants (reference: B=32768, C=2048, smoothing=0.05)
#define SMOOTHING_F   0.05f
#define CONFIDENCE_F  0.95f
#define C_DIM         2048
#define WAVES_PER_BLOCK 4

// d_ws layout: ws[0] = sum(loss) (double), ws[1] = sum(w) (double)

__global__ void ls_zero_ws(double* ws) {
    if (threadIdx.x < 2) ws[threadIdx.x] = 0.0;
}

// One wave per row. Each lane holds 32 row elements in registers (8 x float4),
// single pass over x: max -> sumexp -> lse, plus sum(x) for the smooth term.
__global__ __launch_bounds__(256) void ls_main(
    const float* __restrict__ x,
    const int*   __restrict__ target,
    const float* __restrict__ cw,
    double*      __restrict__ ws,
    int B)
{
    const int lane = threadIdx.x & 63;
    const int wave = threadIdx.x >> 6;

    double loss_acc = 0.0;
    double w_acc    = 0.0;

    int row = blockIdx.x * WAVES_PER_BLOCK + wave;
    for (; row < B; row += gridDim.x * WAVES_PER_BLOCK) {
        const float4* xr = (const float4*)(x + (size_t)row * C_DIM);

        // Coalesced: iteration k reads 64 consecutive float4 (1 KiB/wave).
        float4 v[8];
#pragma unroll
        for (int k = 0; k < 8; ++k) v[k] = xr[lane + 64 * k];

        float m  = -INFINITY;
        float sx = 0.0f;
#pragma unroll
        for (int k = 0; k < 8; ++k) {
            m  = fmaxf(m, fmaxf(fmaxf(v[k].x, v[k].y), fmaxf(v[k].z, v[k].w)));
            sx += (v[k].x + v[k].y) + (v[k].z + v[k].w);
        }
        // wave-wide max (64 lanes)
#pragma unroll
        for (int off = 32; off > 0; off >>= 1)
            m = fmaxf(m, __shfl_xor(m, off, 64));

        float se = 0.0f;
#pragma unroll
        for (int k = 0; k < 8; ++k) {
            se += __expf(v[k].x - m) + __expf(v[k].y - m)
                + __expf(v[k].z - m) + __expf(v[k].w - m);
        }
        // wave-wide sums
#pragma unroll
        for (int off = 32; off > 0; off >>= 1) {
            se += __shfl_xor(se, off, 64);
            sx += __shfl_xor(sx, off, 64);
        }

        if (lane == 0) {
            const float lse    = logf(se) + m;
            const int   t      = target[row];
            const float xt     = x[(size_t)row * C_DIM + t];   // L1/L2 hit
            const float wt     = cw[t];
            const float nll    = lse - xt;
            const float smooth = lse - sx * (1.0f / C_DIM);
            loss_acc += (double)(CONFIDENCE_F * nll * wt + SMOOTHING_F * smooth);
            w_acc    += (double)wt;
        }
    }

    // Block-level reduction, one atomic pair per block.
    __shared__ double s_loss[WAVES_PER_BLOCK];
    __shared__ double s_w[WAVES_PER_BLOCK];
    if (lane == 0) { s_loss[wave] = loss_acc; s_w[wave] = w_acc; }
    __syncthreads();
    if (threadIdx.x == 0) {
        double L = 0.0, W = 0.0;
#pragma unroll
        for (int i = 0; i < WAVES_PER_BLOCK; ++i) { L += s_loss[i]; W += s_w[i]; }
        atomicAdd(&ws[0], L);
        atomicAdd(&ws[1], W);
    }
}

__global__ void ls_finalize(const double* __restrict__ ws, float* __restrict__ out) {
    out[0] = (float)(ws[0] / ws[1]);
}

extern "C" void kernel_launch(void* const* d_in, const int* in_sizes, int n_in,
                              void* d_out, int out_size, void* d_ws, size_t ws_size,
                              hipStream_t stream) {
    const float* x      = (const float*)d_in[0];
    const int*   target = (const int*)  d_in[1];
    const float* cw     = (const float*)d_in[2];
    float*       out    = (float*)d_out;
    double*      ws     = (double*)d_ws;

    const int B = in_sizes[1];  // target has one entry per row

    ls_zero_ws<<<1, 64, 0, stream>>>(ws);

    const int grid = (B + WAVES_PER_BLOCK - 1) / WAVES_PER_BLOCK;  // 8192
    ls_main<<<grid, 64 * WAVES_PER_BLOCK, 0, stream>>>(x, target, cw, ws, B);

    ls_finalize<<<1, 1, 0, stream>>>(ws, out);
}

// Round 2
// 358.923 us; speedup vs baseline: 1.3365x; 1.3365x over previous
//
#include <hip/hip_runtime.h>
#include <math.h>

// Problem: label-smoothed weighted CE. B=32768, C=2048, smoothing=0.05.
#define SMOOTHING_F   0.05f
#define CONFIDENCE_F  0.95f
#define C_DIM         2048
#define WAVES_PER_BLOCK 4
#define GRID_BLOCKS   1024   // 4096 waves, 8 rows/wave at B=32768

// d_ws layout: GRID_BLOCKS double2 partials {sum_loss, sum_w}.
// Every block writes its slot unconditionally -> no zero-init kernel needed.

__global__ __launch_bounds__(256, 4) void ls_main(
    const float* __restrict__ x,
    const int*   __restrict__ target,
    const float* __restrict__ cw,
    double*      __restrict__ ws,   // [GRID_BLOCKS*2] doubles
    int B)
{
    const int lane = threadIdx.x & 63;
    const int wave = threadIdx.x >> 6;
    const int stride = gridDim.x * WAVES_PER_BLOCK;

    double loss_acc = 0.0;
    double w_acc    = 0.0;

    int row = blockIdx.x * WAVES_PER_BLOCK + wave;

    float4 v[8];
    if (row < B) {
        const float4* xr = (const float4*)(x + (size_t)row * C_DIM);
#pragma unroll
        for (int k = 0; k < 8; ++k) v[k] = xr[lane + 64 * k];
    }

    for (; row < B; row += stride) {
        // Broadcast loads for this row's gather terms (same addr across lanes
        // -> single transaction; issued early to overlap with v[] consumption).
        const int   t  = target[row];
        const float wt = cw[t];
        const float xt = x[(size_t)row * C_DIM + t];  // line already inbound

        // Prefetch next row while we reduce the current one.
        const int next = row + stride;
        float4 p[8];
        if (next < B) {
            const float4* xn = (const float4*)(x + (size_t)next * C_DIM);
#pragma unroll
            for (int k = 0; k < 8; ++k) p[k] = xn[lane + 64 * k];
        }

        float m  = -INFINITY;
        float sx = 0.0f;
#pragma unroll
        for (int k = 0; k < 8; ++k) {
            m  = fmaxf(m, fmaxf(fmaxf(v[k].x, v[k].y), fmaxf(v[k].z, v[k].w)));
            sx += (v[k].x + v[k].y) + (v[k].z + v[k].w);
        }
#pragma unroll
        for (int off = 32; off > 0; off >>= 1)
            m = fmaxf(m, __shfl_xor(m, off, 64));

        float se = 0.0f;
#pragma unroll
        for (int k = 0; k < 8; ++k) {
            se += __expf(v[k].x - m) + __expf(v[k].y - m)
                + __expf(v[k].z - m) + __expf(v[k].w - m);
        }
#pragma unroll
        for (int off = 32; off > 0; off >>= 1) {
            se += __shfl_xor(se, off, 64);
            sx += __shfl_xor(sx, off, 64);
        }

        if (lane == 0) {
            const float lse    = logf(se) + m;
            const float nll    = lse - xt;
            const float smooth = lse - sx * (1.0f / C_DIM);
            loss_acc += (double)(CONFIDENCE_F * nll * wt + SMOOTHING_F * smooth);
            w_acc    += (double)wt;
        }

        // Rotate the prefetch buffer in.
#pragma unroll
        for (int k = 0; k < 8; ++k) v[k] = p[k];
    }

    // Block-level reduction (4 waves), one plain double2 store per block.
    __shared__ double s_loss[WAVES_PER_BLOCK];
    __shared__ double s_w[WAVES_PER_BLOCK];
    if (lane == 0) { s_loss[wave] = loss_acc; s_w[wave] = w_acc; }
    __syncthreads();
    if (threadIdx.x == 0) {
        double L = 0.0, W = 0.0;
#pragma unroll
        for (int i = 0; i < WAVES_PER_BLOCK; ++i) { L += s_loss[i]; W += s_w[i]; }
        ws[2 * blockIdx.x]     = L;
        ws[2 * blockIdx.x + 1] = W;
    }
}

// Reduce GRID_BLOCKS double2 partials -> out[0] = sum_loss / sum_w.
__global__ __launch_bounds__(256) void ls_reduce(
    const double* __restrict__ ws, float* __restrict__ out, int nPartials)
{
    const int tid  = threadIdx.x;
    const int lane = tid & 63;
    const int wave = tid >> 6;

    double L = 0.0, W = 0.0;
    for (int i = tid; i < nPartials; i += 256) {
        L += ws[2 * i];
        W += ws[2 * i + 1];
    }
#pragma unroll
    for (int off = 32; off > 0; off >>= 1) {
        L += __shfl_xor(L, off, 64);
        W += __shfl_xor(W, off, 64);
    }
    __shared__ double sL[4], sW[4];
    if (lane == 0) { sL[wave] = L; sW[wave] = W; }
    __syncthreads();
    if (tid == 0) {
        double tL = sL[0] + sL[1] + sL[2] + sL[3];
        double tW = sW[0] + sW[1] + sW[2] + sW[3];
        out[0] = (float)(tL / tW);
    }
}

extern "C" void kernel_launch(void* const* d_in, const int* in_sizes, int n_in,
                              void* d_out, int out_size, void* d_ws, size_t ws_size,
                              hipStream_t stream) {
    const float* x      = (const float*)d_in[0];
    const int*   target = (const int*)  d_in[1];
    const float* cw     = (const float*)d_in[2];
    float*       out    = (float*)d_out;
    double*      ws     = (double*)d_ws;

    const int B = in_sizes[1];  // one target per row

    ls_main<<<GRID_BLOCKS, 64 * WAVES_PER_BLOCK, 0, stream>>>(x, target, cw, ws, B);
    ls_reduce<<<1, 256, 0, stream>>>(ws, out, GRID_BLOCKS);
}